// Round 3
// baseline (1731.229 us; speedup 1.0000x reference)
//
#include <hip/hip_runtime.h>

#define HIDDEN 128
#define QUARTER 32
#define N_RAYS 65536
#define NEAR_D 0.01f
#define FAR_D 10.0f
#define MAX_ITERS 32
#define HSTRIDE 132   // 128 + 4-float pad: measured 0 bank conflicts at this stride

typedef float v2f __attribute__((ext_vector_type(2)));

// d = a*b + d, packed 2xfp32 (v_pk_fma_f32, gfx90a+/CDNA4). Bit-exact fp32 fma.
__device__ __forceinline__ void pk_fma(v2f& d, v2f a, v2f b) {
    asm("v_pk_fma_f32 %0, %1, %2, %0" : "+v"(d) : "v"(a), "v"(b));
}

// Transpose W2 [k][j] -> W2T [j][k] so per-output-row weights are contiguous.
__global__ void w2_transpose_kernel(const float* __restrict__ W2,
                                    float* __restrict__ W2T) {
    int idx = blockIdx.x * blockDim.x + threadIdx.x;   // 0..16383
    int j = idx >> 7;
    int k = idx & 127;
    W2T[j * HIDDEN + k] = W2[k * HIDDEN + j];
}

// Block = 256 threads = 4 waves covering 64 rays (thread = ray, 4-way slice split).
// Wave w owns hidden slice [w*32, w*32+32) and layer-2 output slice [w*32, w*32+32).
// Activations exchanged through LDS each iteration; layer-2 reads all 128 from LDS.
__launch_bounds__(256, 4)
__global__ void sphere_trace_kernel(
    const float* __restrict__ origins,
    const float* __restrict__ directions,
    const float* __restrict__ W1,   // [3][128]
    const float* __restrict__ b1,   // [128]
    const float* __restrict__ W2T,  // [128][128] transposed: W2T[j][k] = W2[k][j]
    const float* __restrict__ b2,   // [128]
    const float* __restrict__ W3,   // [128]
    const float* __restrict__ b3,   // [1]
    const float* __restrict__ Wc1,  // [3][128]
    const float* __restrict__ bc1,  // [128]
    const float* __restrict__ Wc2,  // [128][3]
    const float* __restrict__ bc2,  // [3]
    float* __restrict__ out)        // [N][3]
{
    __shared__ float hbuf[64 * HSTRIDE];   // [ray][128+pad] activations
    __shared__ float part[4][64];          // layer-3 partial sums
    __shared__ float cpart[4][64][3];      // color partial sums

    const int lane = threadIdx.x & 63;
    // Wave-uniform slice id -> all weight addresses wave-uniform.
    const int w = __builtin_amdgcn_readfirstlane(threadIdx.x >> 6);
    const int wbase = w * QUARTER;
    const int ray = blockIdx.x * 64 + lane;

    float px = origins[ray * 3 + 0];
    float py = origins[ray * 3 + 1];
    float pz = origins[ray * 3 + 2];
    const float dx = directions[ray * 3 + 0];
    const float dy = directions[ray * 3 + 1];
    const float dz = directions[ray * 3 + 2];

    float dist = 0.0f;
    bool frozen = false;

    const float* __restrict__ w1w = W1 + wbase;
    const float* __restrict__ b1w = b1 + wbase;
    const float b3v = b3[0];

    #pragma unroll 1
    for (int it = 0; it < MAX_ITERS; ++it) {
        // ---- layer 1 (own 32 units): relu(p @ W1 + b1) -> publish to LDS
        #pragma unroll
        for (int g = 0; g < 8; ++g) {
            const int j0 = 4 * g;
            float4 v;
            v.x = fmaxf(fmaf(px, w1w[j0 + 0], fmaf(py, w1w[HIDDEN + j0 + 0],
                        fmaf(pz, w1w[2 * HIDDEN + j0 + 0], b1w[j0 + 0]))), 0.0f);
            v.y = fmaxf(fmaf(px, w1w[j0 + 1], fmaf(py, w1w[HIDDEN + j0 + 1],
                        fmaf(pz, w1w[2 * HIDDEN + j0 + 1], b1w[j0 + 1]))), 0.0f);
            v.z = fmaxf(fmaf(px, w1w[j0 + 2], fmaf(py, w1w[HIDDEN + j0 + 2],
                        fmaf(pz, w1w[2 * HIDDEN + j0 + 2], b1w[j0 + 2]))), 0.0f);
            v.w = fmaxf(fmaf(px, w1w[j0 + 3], fmaf(py, w1w[HIDDEN + j0 + 3],
                        fmaf(pz, w1w[2 * HIDDEN + j0 + 3], b1w[j0 + 3]))), 0.0f);
            *(float4*)&hbuf[lane * HSTRIDE + wbase + j0] = v;
        }
        __syncthreads();   // B1: activations published

        // ---- layer 2 + 3 (own 32 outputs, 4 blocks of 8), packed fp32 FMA
        float ps = 0.0f;
        #pragma unroll 1
        for (int jb = 0; jb < QUARTER; jb += 8) {
            const int jo = wbase + jb;
            const float* __restrict__ wr = W2T + jo * HIDDEN;
            v2f acc[8];
            #pragma unroll
            for (int o = 0; o < 8; ++o) { acc[o].x = b2[jo + o]; acc[o].y = 0.0f; }

            #pragma unroll
            for (int k4 = 0; k4 < HIDDEN / 4; ++k4) {
                const float4 hv = *(const float4*)&hbuf[lane * HSTRIDE + 4 * k4];
                v2f h01; h01.x = hv.x; h01.y = hv.y;
                v2f h23; h23.x = hv.z; h23.y = hv.w;
                #pragma unroll
                for (int o = 0; o < 8; ++o) {
                    const float4 w4 = *(const float4*)&wr[o * HIDDEN + 4 * k4];
                    v2f w01; w01.x = w4.x; w01.y = w4.y;
                    v2f w23; w23.x = w4.z; w23.y = w4.w;
                    pk_fma(acc[o], h01, w01);
                    pk_fma(acc[o], h23, w23);
                }
            }
            #pragma unroll
            for (int o = 0; o < 8; ++o) {
                const float t = acc[o].x + acc[o].y;
                ps = fmaf(fmaxf(t, 0.0f), W3[jo + o], ps);
            }
        }

        // ---- combine layer-3 partials
        part[w][lane] = ps;
        __syncthreads();   // B2
        const float s = part[0][lane] + part[1][lane] + part[2][lane]
                      + part[3][lane] + b3v;

        // ---- march update (exact reference semantics; all waves identical)
        const bool valid = (s <= NEAR_D) && (dist < FAR_D);
        if (!frozen) {
            if (valid) {
                frozen = true;
            } else {
                dist += s;
                px = fmaf(dx, s, px);
                py = fmaf(dy, s, py);
                pz = fmaf(dz, s, pz);
            }
        }
        // All waves see identical per-lane state -> identical ballot -> uniform break.
        if (__ballot(!frozen) == 0) break;
    }

    const bool mask = frozen || (dist < FAR_D);

    // ---- color MLP, own 32 hidden units -> 3 partial outputs
    const float* __restrict__ wc1w = Wc1 + wbase;
    const float* __restrict__ bc1w = bc1 + wbase;
    const float* __restrict__ wc2w = Wc2 + wbase * 3;

    float a0 = 0.0f, a1 = 0.0f, a2 = 0.0f;
    #pragma unroll
    for (int j = 0; j < QUARTER; ++j) {
        const float hc = fmaxf(fmaf(px, wc1w[j], fmaf(py, wc1w[HIDDEN + j],
                         fmaf(pz, wc1w[2 * HIDDEN + j], bc1w[j]))), 0.0f);
        a0 = fmaf(hc, wc2w[j * 3 + 0], a0);
        a1 = fmaf(hc, wc2w[j * 3 + 1], a1);
        a2 = fmaf(hc, wc2w[j * 3 + 2], a2);
    }
    cpart[w][lane][0] = a0;
    cpart[w][lane][1] = a1;
    cpart[w][lane][2] = a2;
    __syncthreads();

    if (w == 0) {
        float c0 = 0.0f, c1 = 0.0f, c2 = 0.0f;
        if (mask) {
            const float t0 = a0 + cpart[1][lane][0] + cpart[2][lane][0]
                           + cpart[3][lane][0] + bc2[0];
            const float t1 = a1 + cpart[1][lane][1] + cpart[2][lane][1]
                           + cpart[3][lane][1] + bc2[1];
            const float t2 = a2 + cpart[1][lane][2] + cpart[2][lane][2]
                           + cpart[3][lane][2] + bc2[2];
            c0 = 1.0f / (1.0f + __expf(-t0));
            c1 = 1.0f / (1.0f + __expf(-t1));
            c2 = 1.0f / (1.0f + __expf(-t2));
        }
        out[ray * 3 + 0] = c0;
        out[ray * 3 + 1] = c1;
        out[ray * 3 + 2] = c2;
    }
}

extern "C" void kernel_launch(void* const* d_in, const int* in_sizes, int n_in,
                              void* d_out, int out_size, void* d_ws, size_t ws_size,
                              hipStream_t stream) {
    const float* origins    = (const float*)d_in[0];
    const float* directions = (const float*)d_in[1];
    const float* W1  = (const float*)d_in[2];
    const float* b1  = (const float*)d_in[3];
    const float* W2  = (const float*)d_in[4];
    const float* b2  = (const float*)d_in[5];
    const float* W3  = (const float*)d_in[6];
    const float* b3  = (const float*)d_in[7];
    const float* Wc1 = (const float*)d_in[8];
    const float* bc1 = (const float*)d_in[9];
    const float* Wc2 = (const float*)d_in[10];
    const float* bc2 = (const float*)d_in[11];
    float* out = (float*)d_out;

    float* W2T = (float*)d_ws;   // 128*128*4 = 64 KB scratch

    w2_transpose_kernel<<<HIDDEN * HIDDEN / 256, 256, 0, stream>>>(W2, W2T);

    sphere_trace_kernel<<<N_RAYS / 64, 256, 0, stream>>>(
        origins, directions, W1, b1, W2T, b2, W3, b3,
        Wc1, bc1, Wc2, bc2, out);
}

// Round 4
// 1324.770 us; speedup vs baseline: 1.3068x; 1.3068x over previous
//
#include <hip/hip_runtime.h>

#define HIDDEN 128
#define N_RAYS 65536
#define NEAR_D 0.01f
#define FAR_D 10.0f
#define MAX_ITERS 32
#define HSTRIDE 132   // 128 + 4-float pad (rows 16B-aligned; 2-way bank alias = free)

typedef float v2f __attribute__((ext_vector_type(2)));
// Compiler-generated v_pk_fma_f32 (llvm.fma.v2f32 is legal on gfx950). NO inline asm.
__device__ __forceinline__ v2f fma2(v2f a, v2f b, v2f c) {
    return __builtin_elementwise_fma(a, b, c);
}

// Transpose W2 [k][j] -> W2T [j][k]: per-output-row weights contiguous.
__global__ void w2_transpose_kernel(const float* __restrict__ W2,
                                    float* __restrict__ W2T) {
    int idx = blockIdx.x * blockDim.x + threadIdx.x;   // 0..16383
    int j = idx >> 7;
    int k = idx & 127;
    W2T[j * HIDDEN + k] = W2[k * HIDDEN + j];
}

// Block = 256 threads = 4 INDEPENDENT waves. Wave w owns rays [w*16, w*16+16)
// and ALL 128 layer-2 outputs (lane -> outputs 2*lane, 2*lane+1).
// No __syncthreads anywhere: all LDS regions are wave-private, DS ops are
// in-order per wave. Ray state lives in owner lanes 0..15; positions are
// broadcast via pbuf. Early break at 16-ray granularity per wave.
__launch_bounds__(256, 4)
__global__ void sphere_trace_kernel(
    const float* __restrict__ origins,
    const float* __restrict__ directions,
    const float* __restrict__ W1,   // [3][128]
    const float* __restrict__ b1,   // [128]
    const float* __restrict__ W2T,  // [128][128] W2T[j][k] = W2[k][j]
    const float* __restrict__ b2,   // [128]
    const float* __restrict__ W3,   // [128]
    const float* __restrict__ b3,   // [1]
    const float* __restrict__ Wc1,  // [3][128]
    const float* __restrict__ bc1,  // [128]
    const float* __restrict__ Wc2,  // [128][3]
    const float* __restrict__ bc2,  // [3]
    float* __restrict__ out)        // [N][3]
{
    __shared__ float hbuf[64 * HSTRIDE];   // per-wave 16 rows; also reused as
                                           // reduction scratch (h is dead then)
    __shared__ float pbuf[64 * 4];         // per-ray position (x,y,z,-)

    const int lane = threadIdx.x & 63;
    const int w = __builtin_amdgcn_readfirstlane(threadIdx.x >> 6);
    const int hB = w * 16 * HSTRIDE;       // wave's hbuf base (float idx)
    const int j0 = lane * 2;               // this lane's two output columns

    // ---- owner lanes (0..15) hold ray state
    const int lray = w * 16 + (lane & 15); // local ray id (owners)
    const int ray  = blockIdx.x * 64 + lray;
    float px = 0.f, py = 0.f, pz = 0.f, dx = 0.f, dy = 0.f, dz = 0.f;
    float dist = 0.0f;
    bool frozen = true;                    // non-owners permanently inert
    if (lane < 16) {
        px = origins[ray * 3 + 0];
        py = origins[ray * 3 + 1];
        pz = origins[ray * 3 + 2];
        dx = directions[ray * 3 + 0];
        dy = directions[ray * 3 + 1];
        dz = directions[ray * 3 + 2];
        frozen = false;
        float4 p4; p4.x = px; p4.y = py; p4.z = pz; p4.w = 0.f;
        *(float4*)&pbuf[lray * 4] = p4;
    }

    // ---- per-lane invariant weights (loaded once)
    const float w1xe = W1[j0],              w1xo = W1[j0 + 1];
    const float w1ye = W1[HIDDEN + j0],     w1yo = W1[HIDDEN + j0 + 1];
    const float w1ze = W1[2 * HIDDEN + j0], w1zo = W1[2 * HIDDEN + j0 + 1];
    const float b1e = b1[j0], b1o = b1[j0 + 1];
    const float b2e = b2[j0], b2o = b2[j0 + 1];
    const float w3e = W3[j0], w3o = W3[j0 + 1];
    const float b3v = b3[0];
    const float* __restrict__ wE = W2T + j0 * HIDDEN;  // row j0; row j0+1 at +512B imm

    #pragma unroll 1
    for (int it = 0; it < MAX_ITERS; ++it) {
        // ---- layer 1: lane computes h[r][j0], h[r][j0+1] for the wave's 16 rays
        #pragma unroll
        for (int r = 0; r < 16; ++r) {
            const float4 p4 = *(const float4*)&pbuf[(w * 16 + r) * 4]; // broadcast
            const float he = fmaxf(fmaf(p4.x, w1xe, fmaf(p4.y, w1ye,
                             fmaf(p4.z, w1ze, b1e))), 0.0f);
            const float ho = fmaxf(fmaf(p4.x, w1xo, fmaf(p4.y, w1yo,
                             fmaf(p4.z, w1zo, b1o))), 0.0f);
            v2f hv; hv.x = he; hv.y = ho;
            *(v2f*)&hbuf[hB + r * HSTRIDE + j0] = hv;   // b64, 2-way alias = free
        }

        // ---- layer 2: acc[r][0]=col j0, acc[r][1]=col j0+1, pk over k-pairs
        v2f acc[16][2];
        #pragma unroll
        for (int r = 0; r < 16; ++r) { acc[r][0] = (v2f)0.f; acc[r][1] = (v2f)0.f; }

        const float* __restrict__ wp = wE;
        int hoff = hB;
        #pragma unroll 1
        for (int c = 0; c < 32; ++c) {     // one k4 (4 k-values) per chunk
            const float4 wa = *(const float4*)(wp);          // row j0
            const float4 wb = *(const float4*)(wp + HIDDEN); // row j0+1 (+512B imm)
            v2f wa01; wa01.x = wa.x; wa01.y = wa.y;
            v2f wa23; wa23.x = wa.z; wa23.y = wa.w;
            v2f wb01; wb01.x = wb.x; wb01.y = wb.y;
            v2f wb23; wb23.x = wb.z; wb23.y = wb.w;
            #pragma unroll
            for (int r = 0; r < 16; ++r) {
                const float4 h4 = *(const float4*)&hbuf[hoff + r * HSTRIDE]; // broadcast
                v2f h01; h01.x = h4.x; h01.y = h4.y;
                v2f h23; h23.x = h4.z; h23.y = h4.w;
                acc[r][0] = fma2(h01, wa01, acc[r][0]);
                acc[r][0] = fma2(h23, wa23, acc[r][0]);
                acc[r][1] = fma2(h01, wb01, acc[r][1]);
                acc[r][1] = fma2(h23, wb23, acc[r][1]);
            }
            wp += 4; hoff += 4;
        }

        // ---- layer 3 partials: ps[r] = relu(out_e)*W3[j0] + relu(out_o)*W3[j0+1]
        float ps[16];
        #pragma unroll
        for (int r = 0; r < 16; ++r) {
            const float oe = (acc[r][0].x + acc[r][0].y) + b2e;
            const float oo = (acc[r][1].x + acc[r][1].y) + b2o;
            ps[r] = fmaf(fmaxf(oe, 0.0f), w3e,
                    fmaf(fmaxf(oo, 0.0f), w3o, 0.0f));
        }

        // ---- cross-lane reduce through wave-private LDS (aliases dead h rows)
        #pragma unroll
        for (int r = 0; r < 16; ++r)
            hbuf[hB + r * HSTRIDE + lane] = ps[r];

        if (lane < 16) {
            float s = b3v;
            #pragma unroll
            for (int q = 0; q < 16; ++q) {
                const float4 t = *(const float4*)&hbuf[hB + lane * HSTRIDE + 4 * q];
                s += ((t.x + t.y) + (t.z + t.w));
            }
            const bool valid = (s <= NEAR_D) && (dist < FAR_D);
            if (!frozen) {
                if (valid) {
                    frozen = true;
                } else {
                    dist += s;
                    px = fmaf(dx, s, px);
                    py = fmaf(dy, s, py);
                    pz = fmaf(dz, s, pz);
                }
            }
            float4 p4; p4.x = px; p4.y = py; p4.z = pz; p4.w = 0.f;
            *(float4*)&pbuf[lray * 4] = p4;
        }

        const bool notFrozen = (lane < 16) && !frozen;
        if (__ballot(notFrozen) == 0) break;   // wave-uniform: 16-ray early exit
    }

    // ---- color MLP: lane covers hidden units j0, j0+1; butterfly per ray
    const float c1xe = Wc1[j0],              c1xo = Wc1[j0 + 1];
    const float c1ye = Wc1[HIDDEN + j0],     c1yo = Wc1[HIDDEN + j0 + 1];
    const float c1ze = Wc1[2 * HIDDEN + j0], c1zo = Wc1[2 * HIDDEN + j0 + 1];
    const float cb1e = bc1[j0], cb1o = bc1[j0 + 1];
    const float e0 = Wc2[j0 * 3 + 0], e1 = Wc2[j0 * 3 + 1], e2 = Wc2[j0 * 3 + 2];
    const float o0w = Wc2[j0 * 3 + 3], o1w = Wc2[j0 * 3 + 4], o2w = Wc2[j0 * 3 + 5];

    float g0 = 0.f, g1 = 0.f, g2 = 0.f;   // owner lane r grabs ray r's sums
    #pragma unroll 1
    for (int r = 0; r < 16; ++r) {
        const float4 p4 = *(const float4*)&pbuf[(w * 16 + r) * 4]; // broadcast
        const float he = fmaxf(fmaf(p4.x, c1xe, fmaf(p4.y, c1ye,
                         fmaf(p4.z, c1ze, cb1e))), 0.0f);
        const float ho = fmaxf(fmaf(p4.x, c1xo, fmaf(p4.y, c1yo,
                         fmaf(p4.z, c1zo, cb1o))), 0.0f);
        float a0 = fmaf(he, e0, ho * o0w);
        float a1 = fmaf(he, e1, ho * o1w);
        float a2 = fmaf(he, e2, ho * o2w);
        #pragma unroll
        for (int m = 1; m < 64; m <<= 1) {   // 64-lane butterfly (all lanes get sum)
            a0 += __shfl_xor(a0, m);
            a1 += __shfl_xor(a1, m);
            a2 += __shfl_xor(a2, m);
        }
        if (lane == r) { g0 = a0; g1 = a1; g2 = a2; }
    }

    if (lane < 16) {
        float c0 = 0.f, c1 = 0.f, c2 = 0.f;
        if (frozen || dist < FAR_D) {        // frozen==true only via freeze (owners)
            c0 = 1.0f / (1.0f + __expf(-(g0 + bc2[0])));
            c1 = 1.0f / (1.0f + __expf(-(g1 + bc2[1])));
            c2 = 1.0f / (1.0f + __expf(-(g2 + bc2[2])));
        }
        out[ray * 3 + 0] = c0;
        out[ray * 3 + 1] = c1;
        out[ray * 3 + 2] = c2;
    }
}

extern "C" void kernel_launch(void* const* d_in, const int* in_sizes, int n_in,
                              void* d_out, int out_size, void* d_ws, size_t ws_size,
                              hipStream_t stream) {
    const float* origins    = (const float*)d_in[0];
    const float* directions = (const float*)d_in[1];
    const float* W1  = (const float*)d_in[2];
    const float* b1  = (const float*)d_in[3];
    const float* W2  = (const float*)d_in[4];
    const float* b2  = (const float*)d_in[5];
    const float* W3  = (const float*)d_in[6];
    const float* b3  = (const float*)d_in[7];
    const float* Wc1 = (const float*)d_in[8];
    const float* bc1 = (const float*)d_in[9];
    const float* Wc2 = (const float*)d_in[10];
    const float* bc2 = (const float*)d_in[11];
    float* out = (float*)d_out;

    float* W2T = (float*)d_ws;   // 64 KB scratch

    w2_transpose_kernel<<<HIDDEN * HIDDEN / 256, 256, 0, stream>>>(W2, W2T);

    sphere_trace_kernel<<<N_RAYS / 64, 256, 0, stream>>>(
        origins, directions, W1, b1, W2T, b2, W3, b3,
        Wc1, bc1, Wc2, bc2, out);
}

// Round 5
// 1072.420 us; speedup vs baseline: 1.6143x; 1.2353x over previous
//
#include <hip/hip_runtime.h>

#define HIDDEN 128
#define N_RAYS 65536
#define NEAR_D 0.01f
#define FAR_D 10.0f
#define MAX_ITERS 32

typedef _Float16 f16x8 __attribute__((ext_vector_type(8)));
typedef float f32x16 __attribute__((ext_vector_type(16)));

// ---------------------------------------------------------------------------
// Prologue: build W2 B-operand fragment image (fp16 hi limb + lo limb).
// Main-kernel read: lane L, tile t, chunk c, limb l reads 8 halfs at
//   img[l*16384 + (t*8+c)*512 + L*8 + j]  ==  limb_l( W2[k][n] )
// with  n = t*32 + (L&31),  k = c*16 + ((L>>5)&1)*8 + j.
// ---------------------------------------------------------------------------
__global__ void w2_frag_kernel(const float* __restrict__ W2,
                               _Float16* __restrict__ img) {
    int tid = blockIdx.x * blockDim.x + threadIdx.x;   // 0..16383
    int j = tid & 7;
    int L = (tid >> 3) & 63;
    int tc = tid >> 9;                                 // t*8 + c
    int t = tc >> 3, c = tc & 7;
    int n = t * 32 + (L & 31);
    int k = c * 16 + ((L >> 5) & 1) * 8 + j;
    float w = W2[k * HIDDEN + n];
    _Float16 hi = (_Float16)w;
    _Float16 lo = (_Float16)(w - (float)hi);
    img[tid] = hi;
    img[16384 + tid] = lo;
}

// ---------------------------------------------------------------------------
// Main kernel: block = 256 threads = 4 independent waves, 32 rays per wave.
// Per wave-iteration:
//   layer1 : lane computes h[m=lane&31][k in its A-fragment k-set] in regs
//   scale  : per-ray pow2 scale keeps h within f16 range (exact)
//   layer2 : 4 N-tiles x 8 K-chunks x 3 limb-products of mfma_f32_32x32x16_f16
//   layer3 : epilogue relu/dot on C-layout + half-wave butterfly + tiny LDS
//   march  : owner lanes 0..31 hold ray state; exact reference semantics
// No __syncthreads in the loop (weights staged once; everything else
// wave-private).
// ---------------------------------------------------------------------------
__launch_bounds__(256, 2)
__global__ void sphere_trace_kernel(
    const float* __restrict__ origins,
    const float* __restrict__ directions,
    const float* __restrict__ W1,    // [3][128]
    const float* __restrict__ b1,    // [128]
    const _Float16* __restrict__ w2img, // 32768 halfs (hi | lo)
    const float* __restrict__ b2,    // [128]
    const float* __restrict__ W3,    // [128]
    const float* __restrict__ b3,    // [1]
    const float* __restrict__ Wc1,   // [3][128]
    const float* __restrict__ bc1,   // [128]
    const float* __restrict__ Wc2,   // [128][3]
    const float* __restrict__ bc2,   // [3]
    float* __restrict__ out)         // [N][3]
{
    __shared__ __align__(16) _Float16 wlds[32768];   // 64 KB: hi | lo frags
    __shared__ float sbuf[4][32];                    // per-wave s exchange

    const int tid = threadIdx.x;
    const int lane = tid & 63;
    const int w = __builtin_amdgcn_readfirstlane(tid >> 6);
    const int q = lane >> 5;           // half-wave id
    const int n32 = lane & 31;         // my N-column within a tile / my ray id

    // ---- stage weight fragments into LDS (once; only barrier in the kernel)
    {
        const float4* src = (const float4*)w2img;
        float4* dst = (float4*)wlds;
        #pragma unroll
        for (int i = 0; i < 16; ++i)
            dst[tid + 256 * i] = src[tid + 256 * i];
    }
    __syncthreads();

    // ---- ray state (owner lanes 0..31 of each wave)
    const int ray = blockIdx.x * 128 + w * 32 + n32;
    float px = 0.f, py = 0.f, pz = 0.f, dx = 0.f, dy = 0.f, dz = 0.f;
    float dist = 0.0f;
    bool frozen = true;
    if (lane < 32) {
        px = origins[ray * 3 + 0];
        py = origins[ray * 3 + 1];
        pz = origins[ray * 3 + 2];
        dx = directions[ray * 3 + 0];
        dy = directions[ray * 3 + 1];
        dz = directions[ray * 3 + 2];
        frozen = false;
    }

    // ---- per-lane epilogue constants: my 4 output columns n = t*32 + n32
    float b2v[4], w3v[4];
    #pragma unroll
    for (int t = 0; t < 4; ++t) {
        b2v[t] = b2[t * 32 + n32];
        w3v[t] = W3[t * 32 + n32];
    }
    const float b3v = b3[0];
    const int q8 = q * 8;              // my k-offset within a 16-wide chunk

    #pragma unroll 1
    for (int it = 0; it < MAX_ITERS; ++it) {
        // position of my A-row ray (owner lanes broadcast to both halves)
        const float ppx = __shfl(px, n32);
        const float ppy = __shfl(py, n32);
        const float ppz = __shfl(pz, n32);

        // ---- layer 1: h for my ray, my 64 k-values (A-fragment order)
        float hr[64];
        #pragma unroll
        for (int c = 0; c < 8; ++c) {
            const int kb = c * 16 + q8;
            const float* wpx = W1 + kb;
            const float* wpy = W1 + HIDDEN + kb;
            const float* wpz = W1 + 2 * HIDDEN + kb;
            const float* bp  = b1 + kb;
            #pragma unroll
            for (int jj = 0; jj < 8; ++jj) {
                hr[c * 8 + jj] = fmaxf(
                    fmaf(ppx, wpx[jj], fmaf(ppy, wpy[jj],
                    fmaf(ppz, wpz[jj], bp[jj]))), 0.0f);
            }
        }

        // ---- per-ray pow2 scaling (exact) so h fits f16 range
        float mx = 0.0f;
        #pragma unroll
        for (int i = 0; i < 64; ++i) mx = fmaxf(mx, hr[i]);
        mx = fmaxf(mx, __shfl_xor(mx, 32));   // both halves of ray m agree
        float sc = 1.0f, inv = 1.0f;
        {
            const int e = (int)((__float_as_uint(mx) >> 23) & 255u);  // biased
            if (e > 127 + 10) {
                const int sh = e - 137;       // bring max into [1024,2048)
                sc  = __uint_as_float((unsigned)(127 - sh) << 23);
                inv = __uint_as_float((unsigned)(127 + sh) << 23);
            }
        }

        // ---- split h into f16 hi/lo limbs, packed in A-fragment registers
        f16x8 Ah[8], Al[8];
        #pragma unroll
        for (int c = 0; c < 8; ++c) {
            #pragma unroll
            for (int jj = 0; jj < 8; ++jj) {
                const float x = hr[c * 8 + jj] * sc;   // exact (pow2)
                const _Float16 hi = (_Float16)x;
                Ah[c][jj] = hi;
                Al[c][jj] = (_Float16)(x - (float)hi);
            }
        }

        // ---- layer 2: 4 N-tiles x 8 K-chunks x 3 limb products
        f32x16 acc[4];
        #pragma unroll
        for (int t = 0; t < 4; ++t)
            #pragma unroll
            for (int r = 0; r < 16; ++r) acc[t][r] = 0.0f;

        #pragma unroll
        for (int t = 0; t < 4; ++t) {
            #pragma unroll
            for (int c = 0; c < 8; ++c) {
                const int off = ((t * 8 + c) << 9) + (lane << 3);
                const f16x8 bh = *(const f16x8*)(wlds + off);
                const f16x8 bl = *(const f16x8*)(wlds + 16384 + off);
                acc[t] = __builtin_amdgcn_mfma_f32_32x32x16_f16(Ah[c], bh, acc[t], 0, 0, 0);
                acc[t] = __builtin_amdgcn_mfma_f32_32x32x16_f16(Ah[c], bl, acc[t], 0, 0, 0);
                acc[t] = __builtin_amdgcn_mfma_f32_32x32x16_f16(Al[c], bh, acc[t], 0, 0, 0);
            }
        }

        // ---- layer 3: undo scale (per C-row ray), bias, relu, dot W3
        // C row for reg r: m = (r&3) + 8*(r>>2) + 4*q  -> fetch that ray's inv
        float ps[16];
        #pragma unroll
        for (int r = 0; r < 16; ++r) {
            const int msrc = (r & 3) + 8 * (r >> 2) + 4 * q;
            const float invr = __shfl(inv, msrc);
            float p = 0.0f;
            #pragma unroll
            for (int t = 0; t < 4; ++t) {
                const float v = fmaxf(fmaf(acc[t][r], invr, b2v[t]), 0.0f);
                p = fmaf(v, w3v[t], p);
            }
            ps[r] = p;
        }
        // sum over the 32 n-lanes of my half-wave
        #pragma unroll
        for (int mask = 1; mask < 32; mask <<= 1)
            #pragma unroll
            for (int r = 0; r < 16; ++r)
                ps[r] += __shfl_xor(ps[r], mask);
        // lane 0 of each half publishes its 16 rows; owners pick theirs up
        if ((lane & 31) == 0) {
            #pragma unroll
            for (int r = 0; r < 16; ++r)
                sbuf[w][(r & 3) + 8 * (r >> 2) + 4 * q] = ps[r];
        }
        float s = 0.0f;
        if (lane < 32) s = sbuf[w][lane] + b3v;

        // ---- march (exact reference semantics) on owner lanes
        if (lane < 32) {
            const bool valid = (s <= NEAR_D) && (dist < FAR_D);
            if (!frozen) {
                if (valid) {
                    frozen = true;
                } else {
                    dist += s;
                    px = fmaf(dx, s, px);
                    py = fmaf(dy, s, py);
                    pz = fmaf(dz, s, pz);
                }
            }
        }
        if (__ballot((lane < 32) && !frozen) == 0) break;
    }

    // ---- color MLP (runs once): lane owns hidden units k0=lane, k1=lane+64
    const int k0 = lane, k1 = lane + 64;
    const float cx0 = Wc1[k0], cx1 = Wc1[k1];
    const float cy0 = Wc1[HIDDEN + k0], cy1 = Wc1[HIDDEN + k1];
    const float cz0 = Wc1[2 * HIDDEN + k0], cz1 = Wc1[2 * HIDDEN + k1];
    const float cb0 = bc1[k0], cb1 = bc1[k1];
    const float u00 = Wc2[k0 * 3 + 0], u01 = Wc2[k0 * 3 + 1], u02 = Wc2[k0 * 3 + 2];
    const float u10 = Wc2[k1 * 3 + 0], u11 = Wc2[k1 * 3 + 1], u12 = Wc2[k1 * 3 + 2];

    float g0 = 0.f, g1 = 0.f, g2 = 0.f;
    #pragma unroll 1
    for (int m = 0; m < 32; ++m) {
        const float qx = __shfl(px, m);
        const float qy = __shfl(py, m);
        const float qz = __shfl(pz, m);
        const float h0 = fmaxf(fmaf(qx, cx0, fmaf(qy, cy0, fmaf(qz, cz0, cb0))), 0.f);
        const float h1 = fmaxf(fmaf(qx, cx1, fmaf(qy, cy1, fmaf(qz, cz1, cb1))), 0.f);
        float a0 = fmaf(h0, u00, h1 * u10);
        float a1 = fmaf(h0, u01, h1 * u11);
        float a2 = fmaf(h0, u02, h1 * u12);
        #pragma unroll
        for (int mask = 1; mask < 64; mask <<= 1) {
            a0 += __shfl_xor(a0, mask);
            a1 += __shfl_xor(a1, mask);
            a2 += __shfl_xor(a2, mask);
        }
        if (lane == m) { g0 = a0; g1 = a1; g2 = a2; }
    }

    if (lane < 32) {
        float c0 = 0.f, c1 = 0.f, c2 = 0.f;
        if (frozen || dist < FAR_D) {
            c0 = 1.0f / (1.0f + __expf(-(g0 + bc2[0])));
            c1 = 1.0f / (1.0f + __expf(-(g1 + bc2[1])));
            c2 = 1.0f / (1.0f + __expf(-(g2 + bc2[2])));
        }
        out[ray * 3 + 0] = c0;
        out[ray * 3 + 1] = c1;
        out[ray * 3 + 2] = c2;
    }
}

extern "C" void kernel_launch(void* const* d_in, const int* in_sizes, int n_in,
                              void* d_out, int out_size, void* d_ws, size_t ws_size,
                              hipStream_t stream) {
    const float* origins    = (const float*)d_in[0];
    const float* directions = (const float*)d_in[1];
    const float* W1  = (const float*)d_in[2];
    const float* b1  = (const float*)d_in[3];
    const float* W2  = (const float*)d_in[4];
    const float* b2  = (const float*)d_in[5];
    const float* W3  = (const float*)d_in[6];
    const float* b3  = (const float*)d_in[7];
    const float* Wc1 = (const float*)d_in[8];
    const float* bc1 = (const float*)d_in[9];
    const float* Wc2 = (const float*)d_in[10];
    const float* bc2 = (const float*)d_in[11];
    float* out = (float*)d_out;

    _Float16* w2img = (_Float16*)d_ws;   // 64 KB fragment image

    w2_frag_kernel<<<64, 256, 0, stream>>>(W2, w2img);

    sphere_trace_kernel<<<N_RAYS / 128, 256, 0, stream>>>(
        origins, directions, W1, b1, w2img, b2, W3, b3,
        Wc1, bc1, Wc2, bc2, out);
}